// Round 1
// baseline (290.579 us; speedup 1.0000x reference)
//
#include <hip/hip_runtime.h>

#define BB 512
#define TT 4096
#define EPSF 1e-5f

__device__ __forceinline__ void load_row(const float* __restrict__ p, float* dst) {
    const float4* q = reinterpret_cast<const float4*>(p);
#pragma unroll
    for (int i = 0; i < 4; ++i) {
        float4 v = q[i];
        dst[4 * i + 0] = v.x; dst[4 * i + 1] = v.y;
        dst[4 * i + 2] = v.z; dst[4 * i + 3] = v.w;
    }
}

__global__ __launch_bounds__(256) void bimanual_fused_kernel(
    const float* __restrict__ x,       // (B,T,16)
    const float* __restrict__ conv_w,  // (16,8,3)
    const float* __restrict__ conv_b,  // (16,)
    const float* __restrict__ w1,      // (32,16)
    const float* __restrict__ b1,      // (16,)
    const float* __restrict__ w2,      // (16,2)
    const float* __restrict__ b2,      // (2,)
    const float* __restrict__ ln_g,    // (16,)
    const float* __restrict__ ln_b,    // (16,)
    float* __restrict__ out)           // out_X (B*T*16) then alphas (B*T*2)
{
    const int pos = blockIdx.x * blockDim.x + threadIdx.x;   // 0 .. B*T-1
    const int t = pos & (TT - 1);
    const size_t rowbase = (size_t)pos * 16;

    // --- load sliding window rows t-2, t-1, t (zero-pad left) ---
    float xw[3][16];
    load_row(x + rowbase, xw[2]);
    if (t >= 1) {
        load_row(x + rowbase - 16, xw[1]);
    } else {
#pragma unroll
        for (int i = 0; i < 16; ++i) xw[1][i] = 0.f;
    }
    if (t >= 2) {
        load_row(x + rowbase - 32, xw[0]);
    } else {
#pragma unroll
        for (int i = 0; i < 16; ++i) xw[0][i] = 0.f;
    }

    // --- conv (16 out-ch, 8 in-ch, 3 taps), same weights for L and R halves ---
    float h[32];
#pragma unroll
    for (int o = 0; o < 16; ++o) {
        float aL = conv_b[o];
        float aR = aL;
#pragma unroll
        for (int i = 0; i < 8; ++i) {
#pragma unroll
            for (int k = 0; k < 3; ++k) {
                const float w = conv_w[(o * 8 + i) * 3 + k];
                aL = fmaf(xw[k][i], w, aL);
                aR = fmaf(xw[k][8 + i], w, aR);
            }
        }
        h[o]      = fmaxf(aL, 0.f);
        h[16 + o] = fmaxf(aR, 0.f);
    }

    // --- dense1: (32 -> 16) + ReLU ---
    float hid[16];
#pragma unroll
    for (int j = 0; j < 16; ++j) {
        float a = b1[j];
#pragma unroll
        for (int f = 0; f < 32; ++f) {
            a = fmaf(h[f], w1[f * 16 + j], a);
        }
        hid[j] = fmaxf(a, 0.f);
    }

    // --- dense2: (16 -> 2) ---
    float l0 = b2[0], l1 = b2[1];
#pragma unroll
    for (int j = 0; j < 16; ++j) {
        l0 = fmaf(hid[j], w2[j * 2 + 0], l0);
        l1 = fmaf(hid[j], w2[j * 2 + 1], l1);
    }

    // --- softmax over 2 ---
    const float m  = fmaxf(l0, l1);
    const float e0 = __expf(l0 - m);
    const float e1 = __expf(l1 - m);
    const float inv = 1.f / (e0 + e1);
    const float a0 = e0 * inv;
    const float a1 = e1 * inv;

    // --- gated residual: y = x * (1 + alpha_half) ---
    float y[16];
    const float g0 = 1.f + a0;
    const float g1 = 1.f + a1;
#pragma unroll
    for (int i = 0; i < 8; ++i)  y[i]     = xw[2][i]     * g0;
#pragma unroll
    for (int i = 0; i < 8; ++i)  y[8 + i] = xw[2][8 + i] * g1;

    // --- LayerNorm over 16 ---
    float s = 0.f;
#pragma unroll
    for (int i = 0; i < 16; ++i) s += y[i];
    const float mu = s * (1.f / 16.f);
    float v = 0.f;
#pragma unroll
    for (int i = 0; i < 16; ++i) {
        const float d = y[i] - mu;
        v = fmaf(d, d, v);
    }
    const float rs = rsqrtf(v * (1.f / 16.f) + EPSF);

    float o16[16];
#pragma unroll
    for (int i = 0; i < 16; ++i) {
        o16[i] = fmaf((y[i] - mu) * rs, ln_g[i], ln_b[i]);
    }

    // --- stores ---
    float4* od = reinterpret_cast<float4*>(out + rowbase);
#pragma unroll
    for (int i = 0; i < 4; ++i) {
        od[i] = make_float4(o16[4 * i + 0], o16[4 * i + 1],
                            o16[4 * i + 2], o16[4 * i + 3]);
    }
    float2* oa = reinterpret_cast<float2*>(out + (size_t)BB * TT * 16 + (size_t)pos * 2);
    *oa = make_float2(a0, a1);
}

extern "C" void kernel_launch(void* const* d_in, const int* in_sizes, int n_in,
                              void* d_out, int out_size, void* d_ws, size_t ws_size,
                              hipStream_t stream) {
    const float* x      = (const float*)d_in[0];
    const float* conv_w = (const float*)d_in[1];
    const float* conv_b = (const float*)d_in[2];
    const float* w1     = (const float*)d_in[3];
    const float* b1     = (const float*)d_in[4];
    const float* w2     = (const float*)d_in[5];
    const float* b2     = (const float*)d_in[6];
    const float* ln_g   = (const float*)d_in[7];
    const float* ln_b   = (const float*)d_in[8];
    float* out = (float*)d_out;

    const int total = BB * TT;
    dim3 block(256);
    dim3 grid(total / 256);
    hipLaunchKernelGGL(bimanual_fused_kernel, grid, block, 0, stream,
                       x, conv_w, conv_b, w1, b1, w2, b2, ln_g, ln_b, out);
}

// Round 2
// 275.397 us; speedup vs baseline: 1.0551x; 1.0551x over previous
//
#include <hip/hip_runtime.h>

#define BB 512
#define TT 4096
#define EPSF 1e-5f

typedef __attribute__((ext_vector_type(8))) short bf16x8;  // 8 bf16 in 4 VGPRs
typedef __attribute__((ext_vector_type(4))) float f32x4;   // MFMA C/D

// round-to-nearest-even f32 -> bf16 (as raw u16)
__device__ __forceinline__ unsigned short f2b(float f) {
    union { float f; unsigned u; } v; v.f = f;
    unsigned r = (v.u + 0x7fffu + ((v.u >> 16) & 1u)) >> 16;
    return (unsigned short)r;
}

#define XROWB   48     // X tile row pitch: 16 bf16 (32B) padded to 48B (16B-aligned, 2-way banks)
#define HROWB   80     // H tile row pitch: 32 bf16 (64B) padded to 80B (b128-aligned reads)
#define HIDROWB 80     // HID tile row pitch: 16 f32 (64B) padded to 80B
#define H_OFF   20480  // H region offset; region0 [0,20480) = X (258*48) then reused as HID (256*80)

__global__ __launch_bounds__(256) void bimanual_mfma_kernel(
    const float* __restrict__ x,       // (B,T,16)
    const float* __restrict__ conv_w,  // (16,8,3)
    const float* __restrict__ conv_b,  // (16,)
    const float* __restrict__ w1,      // (32,16)
    const float* __restrict__ b1,      // (16,)
    const float* __restrict__ w2,      // (16,2)
    const float* __restrict__ b2,      // (2,)
    const float* __restrict__ ln_g,    // (16,)
    const float* __restrict__ ln_b,    // (16,)
    float* __restrict__ out)           // out_X (B*T*16) then alphas (B*T*2)
{
    __shared__ __align__(16) unsigned char lds[40960];

    const int tid  = threadIdx.x;
    const int lane = tid & 63;
    const int w    = tid >> 6;        // wave id 0..3, owns positions [64w, 64w+64)
    const int col  = lane & 15;       // MFMA: A-row / B-col / D-col
    const int g    = lane >> 4;       // MFMA: k-group (A/B), D row-group
    const int p0   = blockIdx.x << 8; // first global position of this block

    // ---- per-lane weight fragments (one-time scattered global loads) ----
    // conv B: B[k = tap*8 + ich][col=och] = conv_w[och][ich][tap]; k-group g = tap, g==3 zero
    // dense1 B: B[k = feat][col=hid] = w1[feat*16 + hid]
    bf16x8 Bc, B1;
#pragma unroll
    for (int j = 0; j < 8; ++j) {
        float wc = (g < 3) ? conv_w[(col * 8 + j) * 3 + g] : 0.f;
        Bc[j] = (short)f2b(wc);
        B1[j] = (short)f2b(w1[(g * 8 + j) * 16 + col]);
    }
    const float bias_c = conv_b[col];
    const float bias_1 = b1[col];

    // ---- phase 1: stage x (rows t0-2 .. t0+255) as bf16 into X tile ----
    const bool tz = ((blockIdx.x & 15) == 0);  // t0 == 0 -> rows 0,1 are zero-pad
    for (int r = tid; r < 258; r += 256) {
        unsigned u[8];
        if (tz && r < 2) {
#pragma unroll
            for (int k = 0; k < 8; ++k) u[k] = 0u;
        } else {
            const float4* src = reinterpret_cast<const float4*>(x + (size_t)(p0 + r - 2) * 16);
            float f[16];
#pragma unroll
            for (int k = 0; k < 4; ++k) {
                float4 v = src[k];
                f[4 * k] = v.x; f[4 * k + 1] = v.y; f[4 * k + 2] = v.z; f[4 * k + 3] = v.w;
            }
#pragma unroll
            for (int k = 0; k < 8; ++k)
                u[k] = (unsigned)f2b(f[2 * k]) | ((unsigned)f2b(f[2 * k + 1]) << 16);
        }
        *reinterpret_cast<uint4*>(lds + r * XROWB)      = make_uint4(u[0], u[1], u[2], u[3]);
        *reinterpret_cast<uint4*>(lds + r * XROWB + 16) = make_uint4(u[4], u[5], u[6], u[7]);
    }
    __syncthreads();

    // ---- phase 2: conv via MFMA; M=16 positions per tile, L/R halves share weights ----
    const bf16x8 zfrag = {0, 0, 0, 0, 0, 0, 0, 0};
#pragma unroll
    for (int m = 0; m < 4; ++m) {
        const int posm = (w << 6) + (m << 4);
        // A: row=position (lane&15), k-group g = tap -> X row = pos + g; lane reads its 8 ch contiguously
        const int arow = posm + col + ((g < 3) ? g : 0);
        bf16x8 AL = *reinterpret_cast<const bf16x8*>(lds + arow * XROWB);       // ch 0-7 (L)
        bf16x8 AR = *reinterpret_cast<const bf16x8*>(lds + arow * XROWB + 16);  // ch 8-15 (R)
        if (g == 3) { AL = zfrag; AR = zfrag; }
        f32x4 accL = {bias_c, bias_c, bias_c, bias_c};
        f32x4 accR = accL;
        accL = __builtin_amdgcn_mfma_f32_16x16x32_bf16(AL, Bc, accL, 0, 0, 0);
        accR = __builtin_amdgcn_mfma_f32_16x16x32_bf16(AR, Bc, accR, 0, 0, 0);
        // D: col = out-ch (lane&15), row = g*4+q -> ReLU, bf16, store H_cat[pos][feat]
        const int prow = posm + (g << 2);
#pragma unroll
        for (int q = 0; q < 4; ++q) {
            *reinterpret_cast<unsigned short*>(lds + H_OFF + (prow + q) * HROWB + col * 2)
                = f2b(fmaxf(accL[q], 0.f));
            *reinterpret_cast<unsigned short*>(lds + H_OFF + (prow + q) * HROWB + 32 + col * 2)
                = f2b(fmaxf(accR[q], 0.f));
        }
    }
    __syncthreads();

    // ---- phase 3: dense1 (32 -> 16) via MFMA; HID (f32) reuses X region ----
#pragma unroll
    for (int m = 0; m < 4; ++m) {
        const int posm = (w << 6) + (m << 4);
        bf16x8 A = *reinterpret_cast<const bf16x8*>(
            lds + H_OFF + (posm + col) * HROWB + g * 16);  // lane: 8 feats of its position
        f32x4 acc = {bias_1, bias_1, bias_1, bias_1};
        acc = __builtin_amdgcn_mfma_f32_16x16x32_bf16(A, B1, acc, 0, 0, 0);
        const int prow = posm + (g << 2);
#pragma unroll
        for (int q = 0; q < 4; ++q)
            *reinterpret_cast<float*>(lds + (prow + q) * HIDROWB + col * 4) = fmaxf(acc[q], 0.f);
    }
    __syncthreads();

    // ---- phase 4: per-position dense2 + softmax + gated residual + LayerNorm (f32) ----
    float hid[16];
    const float4* hp = reinterpret_cast<const float4*>(lds + tid * HIDROWB);
#pragma unroll
    for (int k = 0; k < 4; ++k) {
        float4 v = hp[k];
        hid[4 * k] = v.x; hid[4 * k + 1] = v.y; hid[4 * k + 2] = v.z; hid[4 * k + 3] = v.w;
    }
    float l0 = b2[0], l1 = b2[1];
#pragma unroll
    for (int j = 0; j < 16; ++j) {
        l0 = fmaf(hid[j], w2[2 * j], l0);
        l1 = fmaf(hid[j], w2[2 * j + 1], l1);
    }
    const float mm = fmaxf(l0, l1);
    const float e0 = __expf(l0 - mm);
    const float e1 = __expf(l1 - mm);
    const float inv = 1.f / (e0 + e1);
    const float a0 = e0 * inv;
    const float a1 = e1 * inv;

    // exact x (f32) reload — L2/L3 resident from phase 1
    const size_t rowbase = (size_t)(p0 + tid) * 16;
    float xv[16];
    const float4* xp = reinterpret_cast<const float4*>(x + rowbase);
#pragma unroll
    for (int k = 0; k < 4; ++k) {
        float4 v = xp[k];
        xv[4 * k] = v.x; xv[4 * k + 1] = v.y; xv[4 * k + 2] = v.z; xv[4 * k + 3] = v.w;
    }
    float y[16];
    const float g0 = 1.f + a0;
    const float g1 = 1.f + a1;
#pragma unroll
    for (int i = 0; i < 8; ++i) y[i] = xv[i] * g0;
#pragma unroll
    for (int i = 0; i < 8; ++i) y[8 + i] = xv[8 + i] * g1;

    float s = 0.f;
#pragma unroll
    for (int i = 0; i < 16; ++i) s += y[i];
    const float mu = s * (1.f / 16.f);
    float var = 0.f;
#pragma unroll
    for (int i = 0; i < 16; ++i) {
        const float d = y[i] - mu;
        var = fmaf(d, d, var);
    }
    const float rs = rsqrtf(var * (1.f / 16.f) + EPSF);

    float4* od = reinterpret_cast<float4*>(out + rowbase);
#pragma unroll
    for (int k = 0; k < 4; ++k) {
        float o0 = fmaf((y[4 * k]     - mu) * rs, ln_g[4 * k],     ln_b[4 * k]);
        float o1 = fmaf((y[4 * k + 1] - mu) * rs, ln_g[4 * k + 1], ln_b[4 * k + 1]);
        float o2 = fmaf((y[4 * k + 2] - mu) * rs, ln_g[4 * k + 2], ln_b[4 * k + 2]);
        float o3 = fmaf((y[4 * k + 3] - mu) * rs, ln_g[4 * k + 3], ln_b[4 * k + 3]);
        od[k] = make_float4(o0, o1, o2, o3);
    }
    *reinterpret_cast<float2*>(out + (size_t)BB * TT * 16 + (size_t)(p0 + tid) * 2)
        = make_float2(a0, a1);
}

extern "C" void kernel_launch(void* const* d_in, const int* in_sizes, int n_in,
                              void* d_out, int out_size, void* d_ws, size_t ws_size,
                              hipStream_t stream) {
    const float* x      = (const float*)d_in[0];
    const float* conv_w = (const float*)d_in[1];
    const float* conv_b = (const float*)d_in[2];
    const float* w1     = (const float*)d_in[3];
    const float* b1     = (const float*)d_in[4];
    const float* w2     = (const float*)d_in[5];
    const float* b2     = (const float*)d_in[6];
    const float* ln_g   = (const float*)d_in[7];
    const float* ln_b   = (const float*)d_in[8];
    float* out = (float*)d_out;

    const int total = BB * TT;
    dim3 block(256);
    dim3 grid(total / 256);
    hipLaunchKernelGGL(bimanual_mfma_kernel, grid, block, 0, stream,
                       x, conv_w, conv_b, w1, b1, w2, b2, ln_g, ln_b, out);
}